// Round 14
// baseline (245.276 us; speedup 1.0000x reference)
//
#include <hip/hip_runtime.h>
#include <stdint.h>

#define BATCH 64
#define CDIM  64
#define NPTS  1024
#define ODIM  128
#define KNN   49
#define KNNP  52      // fallback-path knn row stride
#define BNEPS 1e-5f
#define ZPAD  72      // ZF row stride in ushorts (144 B: 16B-aligned, 2-way banks)

typedef __attribute__((ext_vector_type(8))) short bf16x8;   // 8 bf16 (4 VGPRs)
typedef __attribute__((ext_vector_type(4))) float f32x4;
typedef union { bf16x8 v; uint32_t d[4]; } bfu;

__device__ __forceinline__ int mbcnt64(unsigned long long m) {
    return __builtin_amdgcn_mbcnt_hi((uint32_t)(m >> 32),
           __builtin_amdgcn_mbcnt_lo((uint32_t)m, 0));
}

__device__ __forceinline__ void bf16_split(float x, uint32_t& h, uint32_t& l) {
    uint32_t u = __float_as_uint(x);
    h = (u + 0x7FFFu + ((u >> 16) & 1u)) >> 16;      // RTNE bf16 high part
    float hf = __uint_as_float(h << 16);
    uint32_t ul = __float_as_uint(x - hf);
    l = (ul + 0x7FFFu + ((ul >> 16) & 1u)) >> 16;    // RTNE bf16 residual
}

// ---- workspace layout (bytes) ----
#define O_XF   0
#define SZ_XF  (BATCH*64*2*64*8*4)        // 16,777,216  X Gram fragments (k1)
#define O_SQ   (O_XF + SZ_XF)
#define SZ_SQ  (BATCH*NPTS*4)             // 262,144    per-col squared norms
#define O_WF   (O_SQ + SZ_SQ)             // W bf16 hi/lo B-fragments (32 KB)
#define SZ_WF  (2*16*64*16)
#define O_PAD  (O_WF + SZ_WF)
#define SZ_PAD (13631488 - SZ_WF)         // keep XFT at its proven offset
#define O_XFT  (O_PAD + SZ_PAD)
#define SZ_XFT (BATCH*32*4*64*8*4)        // 16,777,216 X^T agg B-fragments
#define WS_NEED ((size_t)(O_XFT + SZ_XFT))  // 47,448,064 == round-4 proven bound

// out[b*O+o] = beta - gamma*mean*rsqrt(var+eps)   (fallback path init)
__global__ void gcn_init(const float* __restrict__ gamma, const float* __restrict__ beta,
                         const float* __restrict__ rmean, const float* __restrict__ rvar,
                         float* __restrict__ out) {
    int i = blockIdx.x * 256 + threadIdx.x;
    if (i < BATCH * ODIM) {
        int o = i & (ODIM - 1);
        out[i] = beta[o] - gamma[o] * rmean[o] * rsqrtf(rvar[o] + BNEPS);
    }
}

// ======================= K0: Gram frags + agg B-frags (X^T) + W frags + sq ==============
// Blocks 0-31 also init out (BN constant); blocks 32-35 also write the pre-split W
// B-fragments (WFh/WFl). Every block builds 8 XFT fragment tiles.
__global__ __launch_bounds__(256) void k0_split(const float* __restrict__ X,
                                                const float* __restrict__ W,
                                                uint32_t* __restrict__ XF,
                                                float* __restrict__ sq,
                                                uint32_t* __restrict__ XFT,
                                                uint32_t* __restrict__ WFh,
                                                uint32_t* __restrict__ WFl,
                                                const float* __restrict__ gamma,
                                                const float* __restrict__ beta,
                                                const float* __restrict__ rmean,
                                                const float* __restrict__ rvar,
                                                float* __restrict__ out) {
    if (blockIdx.x < 32) {                           // 32*256 = 8192 = BATCH*ODIM
        int i = blockIdx.x * 256 + threadIdx.x;
        int o = i & (ODIM - 1);
        out[i] = beta[o] - gamma[o] * rmean[o] * rsqrtf(rvar[o] + BNEPS);
    } else if (blockIdx.x < 36) {                    // 4*256 = 1024 = 16 entries x 64 lanes
        int item = (blockIdx.x - 32) * 256 + threadIdx.x;
        int e = item >> 6, ln = item & 63;
        int nt = e >> 1, kt = e & 1;
        int o = nt * 16 + (ln & 15);
        int kc = kt * 32 + (ln >> 4) * 8;            // B-frag: k = quad*8 + j
        const float* wp = W + (size_t)o * CDIM + kc;
        uint32_t h[8], l[8];
#pragma unroll
        for (int jj = 0; jj < 8; jj++) bf16_split(wp[jj], h[jj], l[jj]);
        *(uint4*)&WFh[item * 4] = make_uint4(h[0] | (h[1] << 16), h[2] | (h[3] << 16),
                                             h[4] | (h[5] << 16), h[6] | (h[7] << 16));
        *(uint4*)&WFl[item * 4] = make_uint4(l[0] | (l[1] << 16), l[2] | (l[3] << 16),
                                             l[4] | (l[5] << 16), l[6] | (l[7] << 16));
    }
    const int b    = blockIdx.x >> 4;
    const int g    = blockIdx.x & 15;
    const int wv   = threadIdx.x >> 6;
    const int t16  = g * 4 + wv;
    const int lane = threadIdx.x & 63;
    const int n    = t16 * 16 + (lane & 15);
    const int cg   = lane >> 4;
    const float* Xb = X + (size_t)b * CDIM * NPTS;
    float s = 0.f;
    for (int ks = 0; ks < 2; ks++) {                 // ---- Gram fragments (k1) ----
        uint32_t hi[4], lo[4];
#pragma unroll
        for (int dj = 0; dj < 4; dj++) {
            uint32_t hw[2], lw[2];
#pragma unroll
            for (int e = 0; e < 2; e++) {
                int c = ks * 32 + cg * 8 + dj * 2 + e;
                float x = Xb[(size_t)c * NPTS + n];
                s += x * x;
                bf16_split(x, hw[e], lw[e]);
            }
            hi[dj] = hw[0] | (hw[1] << 16);
            lo[dj] = lw[0] | (lw[1] << 16);
        }
        size_t entry = ((size_t)(b * 64 + t16) * 2 + ks) * 64 + lane;
        uint32_t* p = XF + entry * 8;
        *(uint4*)p       = make_uint4(hi[0], hi[1], hi[2], hi[3]);
        *(uint4*)(p + 4) = make_uint4(lo[0], lo[1], lo[2], lo[3]);
    }
    s += __shfl_xor(s, 16, 64);
    s += __shfl_xor(s, 32, 64);
    if (lane < 16) sq[b * NPTS + n] = s;

    // ---- agg B-fragments: B[k=node][n=channel] = X[c][node], hi/lo split ----
#pragma unroll
    for (int sx = 0; sx < 2; sx++) {
        int task = g * 8 + wv * 2 + sx;              // 0..127 = 32 kt x 4 ct
        int kt = task >> 2, ct = task & 3;
        int c  = ct * 16 + (lane & 15);
        int n0 = kt * 32 + (lane >> 4) * 8;
        const float* xp = Xb + (size_t)c * NPTS + n0;
        uint32_t h[8], l[8];
#pragma unroll
        for (int j = 0; j < 8; j++) bf16_split(xp[j], h[j], l[j]);
        uint32_t* pp = XFT + ((((size_t)b * 32 + kt) * 4 + ct) * 64 + lane) * 8;
        *(uint4*)pp       = make_uint4(h[0] | (h[1] << 16), h[2] | (h[3] << 16),
                                       h[4] | (h[5] << 16), h[6] | (h[7] << 16));
        *(uint4*)(pp + 4) = make_uint4(l[0] | (l[1] << 16), l[2] | (l[3] << 16),
                                       l[4] | (l[5] << 16), l[6] | (l[7] << 16));
    }
}

// ======================= K1: Gram + select + agg-MFMA + W-GEMM + BN/pool (FUSED) ========
// Select path = round-8 frozen config. Emit: __ballot(sel) per (row,tt) IS the
// neighbor bitmap (no knn array, no scattered stores, no RMW amplification). Tail:
// agg z = S*Xhi + S*Xlo via MFMA (A from bitmap bytes, B from XFT), combine, bf16
// split to ZF, W-GEMM with pre-split WF fragments, fused relu/bias/BN/pool atomics.
__global__ __launch_bounds__(512, 6) void k1_fused(const uint32_t* __restrict__ XF,
                                                   const float* __restrict__ sq,
                                                   const uint32_t* __restrict__ XFT,
                                                   const uint32_t* __restrict__ WFh,
                                                   const uint32_t* __restrict__ WFl,
                                                   const float* __restrict__ bias,
                                                   const float* __restrict__ gamma,
                                                   const float* __restrict__ rvar,
                                                   float* __restrict__ out) {
    __shared__ uint32_t s_pk[8 * 1024];              // 32 KB packed keys; tail reuse
    __shared__ uint32_t bm[16][33];                  // 2.1 KB row bitmaps (padded)
    const int b    = blockIdx.x >> 6;
    const int rt   = blockIdx.x & 63;                // 16-row tile
    const int wave = threadIdx.x >> 6, lane = threadIdx.x & 63;
    const int q = lane >> 4, l15 = lane & 15;

    // ---- Gram (frozen) ----
    bf16x8 ahi[2], alo[2];
#pragma unroll
    for (int ks = 0; ks < 2; ks++) {
        const uint32_t* p = XF + (((size_t)(b * 64 + rt) * 2 + ks) * 64 + lane) * 8;
        ahi[ks] = *(const bf16x8*)p;
        alo[ks] = *(const bf16x8*)(p + 4);
    }
    const float* sqb = sq + b * NPTS;

#pragma unroll
    for (int tt = 0; tt < 8; tt++) {                 // wave's 8 col-tiles
        const int t16 = wave * 8 + tt;
        f32x4 acc = {0.f, 0.f, 0.f, 0.f};
#pragma unroll
        for (int ks = 0; ks < 2; ks++) {
            const uint32_t* p = XF + (((size_t)(b * 64 + t16) * 2 + ks) * 64 + lane) * 8;
            bf16x8 bhi = *(const bf16x8*)p;
            bf16x8 blo = *(const bf16x8*)(p + 4);
            acc = __builtin_amdgcn_mfma_f32_16x16x32_bf16(ahi[ks], bhi, acc, 0, 0, 0);
            acc = __builtin_amdgcn_mfma_f32_16x16x32_bf16(alo[ks], bhi, acc, 0, 0, 0);
            acc = __builtin_amdgcn_mfma_f32_16x16x32_bf16(ahi[ks], blo, acc, 0, 0, 0);
        }
        const int col  = t16 * 16 + l15;
        const float sqv = sqb[col];
        uint32_t k16[4];
#pragma unroll
        for (int i = 0; i < 4; i++) {
            int row = q * 4 + i;                     // C layout: row=(lane>>4)*4+reg
            float d = fmaf(-2.f, acc[i], sqv);       // sq_r dropped (row-monotone)
            if (col == rt * 16 + row) d = __uint_as_float(0x7F800000u);  // self
            uint32_t u = __float_as_uint(d);
            uint32_t key = ((int)u < 0) ? ~u : (u | 0x80000000u);
            k16[i] = key >> 16;                      // 16-bit monotone key
        }
        const int p0 = 2 * q, p1 = 2 * q + 1;        // row pairs (2-way wr conflict: free)
        s_pk[p0 * 1024 + (col ^ ((p0 & 3) << 3))] = k16[0] | (k16[1] << 16);
        s_pk[p1 * 1024 + (col ^ ((p1 & 3) << 3))] = k16[2] | (k16[3] << 16);
    }
    __syncthreads();

    // ---- select (frozen): keys -> regs, narrowed 16-bit binary search ----
    uint32_t k0r[16], k1r[16];
    {
        const int sw = (wave & 3) << 3;
#pragma unroll
        for (int tt = 0; tt < 16; tt++) {
            uint32_t pk = s_pk[wave * 1024 + ((tt * 64 + lane) ^ sw)];
            k0r[tt] = pk & 0xFFFFu;
            k1r[tt] = pk >> 16;
        }
    }

    uint32_t lo0, hi0, lo1, hi1;
    {
        uint32_t lm0 = k0r[0], lm1 = k1r[0];
#pragma unroll
        for (int tt = 1; tt < 16; tt++) {
            lm0 = k0r[tt] < lm0 ? k0r[tt] : lm0;
            lm1 = k1r[tt] < lm1 ? k1r[tt] : lm1;
        }
        uint32_t g0 = lm0, m0 = lm0, g1 = lm1, m1 = lm1;
#pragma unroll
        for (int off = 1; off < 64; off <<= 1) {
            uint32_t a0 = (uint32_t)__shfl_xor((int)g0, off, 64);
            uint32_t b0 = (uint32_t)__shfl_xor((int)m0, off, 64);
            uint32_t a1 = (uint32_t)__shfl_xor((int)g1, off, 64);
            uint32_t b1 = (uint32_t)__shfl_xor((int)m1, off, 64);
            g0 = a0 < g0 ? a0 : g0;  m0 = b0 > m0 ? b0 : m0;
            g1 = a1 < g1 ? a1 : g1;  m1 = b1 > m1 ? b1 : m1;
        }
        lo0 = g0; hi0 = m0;                          // cnt(<=m) >= 64 >= KNN
        lo1 = g1; hi1 = m1;
    }

    for (int it = 0; it < 16; it++) {
        bool a0 = lo0 < hi0, a1 = lo1 < hi1;
        if (!a0 && !a1) break;
        uint32_t mid0 = (lo0 + hi0) >> 1;
        uint32_t mid1 = (lo1 + hi1) >> 1;
        int cnt0 = 0, cnt1 = 0;
#pragma unroll
        for (int tt = 0; tt < 16; tt++) {
            cnt0 += __popcll(__ballot(k0r[tt] <= mid0));
            cnt1 += __popcll(__ballot(k1r[tt] <= mid1));
        }
        if (a0) { if (cnt0 >= KNN) hi0 = mid0; else lo0 = mid0 + 1; }
        if (a1) { if (cnt1 >= KNN) hi1 = mid1; else lo1 = mid1 + 1; }
    }

    // ---- emit: selection ballots ARE the bitmap (no knn, no scattered stores) ----
#pragma unroll
    for (int r = 0; r < 2; r++) {
        const int row = wave * 2 + r;
        const uint32_t vstar = r ? lo1 : lo0;
        const uint32_t* k = r ? k1r : k0r;
        int total_lt = 0;
#pragma unroll
        for (int tt = 0; tt < 16; tt++)
            total_lt += __popcll(__ballot(k[tt] < vstar));
        int base_eq = total_lt;                      // total_lt <= 48 by minimality
#pragma unroll
        for (int tt = 0; tt < 16; tt++) {
            bool islt = k[tt] < vstar;
            bool iseq = k[tt] == vstar;
            unsigned long long meq = __ballot(iseq);
            int pos = base_eq + mbcnt64(meq);
            bool sel = islt || (iseq && pos < KNN);
            unsigned long long msel = __ballot(sel);
            if (lane < 2)
                bm[row][tt * 2 + lane] = lane ? (uint32_t)(msel >> 32) : (uint32_t)msel;
            base_eq += __popcll(meq);
        }
    }
    __syncthreads();                                 // bitmap complete; s_pk dead

    // ---- agg-MFMA: z[16 rows][64 ch] = S*Xhi + S*Xlo. wave = (ct, kt-half) ----
    float* redp = (float*)s_pk;                      // [8][64][4] partial C tiles (8 KB)
    uint16_t* ZFh = (uint16_t*)(s_pk + 2048);        // [16][ZPAD] z hi (2.3 KB)
    uint16_t* ZFl = ZFh + 16 * ZPAD;                 // [16][ZPAD] z lo
    {
        const int ct = wave >> 1, kh = wave & 1;
        f32x4 za = {0.f, 0.f, 0.f, 0.f};
#pragma unroll
        for (int ki = 0; ki < 16; ki++) {
            const int kt = kh * 16 + ki;
            const uint32_t* p = XFT + ((((size_t)b * 32 + kt) * 4 + ct) * 64 + lane) * 8;
            bf16x8 bhi = *(const bf16x8*)p;
            bf16x8 blo = *(const bf16x8*)(p + 4);
            uint32_t byte = (bm[l15][kt] >> (q * 8)) & 0xFFu;
            bfu a;                                   // bf16 1.0 = 0x3F80 per set bit
            a.d[0] = ((byte & 1u)  ? 0x3F80u : 0u) | ((byte & 2u)   ? 0x3F800000u : 0u);
            a.d[1] = ((byte & 4u)  ? 0x3F80u : 0u) | ((byte & 8u)   ? 0x3F800000u : 0u);
            a.d[2] = ((byte & 16u) ? 0x3F80u : 0u) | ((byte & 32u)  ? 0x3F800000u : 0u);
            a.d[3] = ((byte & 64u) ? 0x3F80u : 0u) | ((byte & 128u) ? 0x3F800000u : 0u);
            za = __builtin_amdgcn_mfma_f32_16x16x32_bf16(a.v, bhi, za, 0, 0, 0);
            za = __builtin_amdgcn_mfma_f32_16x16x32_bf16(a.v, blo, za, 0, 0, 0);
        }
        *(f32x4*)&redp[(wave * 64 + lane) * 4] = za;
    }
    __syncthreads();
    if (wave < 4) {                                  // combine kt-halves; split -> ZF
        const int ctw = wave;
        f32x4 za = *(const f32x4*)&redp[((2 * ctw) * 64 + lane) * 4];
        f32x4 zb = *(const f32x4*)&redp[((2 * ctw + 1) * 64 + lane) * 4];
#pragma unroll
        for (int i = 0; i < 4; i++) {                // C: row=q*4+i, col=ctw*16+l15
            uint32_t h, l;
            bf16_split(za[i] + zb[i], h, l);
            const int rr = q * 4 + i, cc = ctw * 16 + l15;
            ZFh[rr * ZPAD + cc] = (uint16_t)h;
            ZFl[rr * ZPAD + cc] = (uint16_t)l;
        }
    }
    __syncthreads();

    // ---- W-GEMM: wave = nt; S[row][o] = sum_c z[row][c]*W[o][c]; BN/pool ----
    {
        const int nt = wave, o = nt * 16 + l15;
        bf16x8 zah[2], zal[2];
#pragma unroll
        for (int kt = 0; kt < 2; kt++) {             // A: m=l15, k=q*8+j
            const int kb = kt * 32 + q * 8;
            zah[kt] = *(const bf16x8*)&ZFh[l15 * ZPAD + kb];
            zal[kt] = *(const bf16x8*)&ZFl[l15 * ZPAD + kb];
        }
        bfu wh[2], wl[2];
#pragma unroll
        for (int kt = 0; kt < 2; kt++) {             // pre-split W fragments (coalesced)
            const int item = (nt * 2 + kt) * 64 + lane;
            *(uint4*)wh[kt].d = *(const uint4*)&WFh[item * 4];
            *(uint4*)wl[kt].d = *(const uint4*)&WFl[item * 4];
        }
        f32x4 accw = {0.f, 0.f, 0.f, 0.f};
#pragma unroll
        for (int kt = 0; kt < 2; kt++) {
            accw = __builtin_amdgcn_mfma_f32_16x16x32_bf16(zah[kt], wh[kt].v, accw, 0, 0, 0);
            accw = __builtin_amdgcn_mfma_f32_16x16x32_bf16(zal[kt], wh[kt].v, accw, 0, 0, 0);
            accw = __builtin_amdgcn_mfma_f32_16x16x32_bf16(zah[kt], wl[kt].v, accw, 0, 0, 0);
        }
        const float bo = bias[o];
        float s = 0.f;
#pragma unroll
        for (int reg = 0; reg < 4; reg++)            // C: row=q*4+reg, col=l15
            s += fmaxf(fmaf(accw[reg], 1.f / KNN, bo), 0.f);
        s += __shfl_xor(s, 16, 64);                  // sum over q -> 16 rows
        s += __shfl_xor(s, 32, 64);
        if (lane < 16) {
            float scale = gamma[o] * rsqrtf(rvar[o] + BNEPS) * (1.f / NPTS);
            atomicAdd(&out[b * ODIM + o], s * scale);
        }
    }
}

// ======================= Fallback: round-1 fused kernel (no workspace) ==================
#define RTILE 8
#define APAD  1028
#define WPAD  132
#define POOLF (64 * WPAD)

__global__ __launch_bounds__(256) void gcn_main(
    const float* __restrict__ X, const float* __restrict__ W,
    const float* __restrict__ bias, const float* __restrict__ gamma,
    const float* __restrict__ rvar, float* __restrict__ out)
{
    __shared__ __align__(16) float s_pool[POOLF];
    __shared__ __align__(16) float s_fstage[4][APAD];
    __shared__ int   s_knn[RTILE][KNN];
    __shared__ float s_z[RTILE][CDIM];

    const int t = threadIdx.x;
    const int b = blockIdx.x >> 7;
    const int rtile = blockIdx.x & 127;
    const int r0 = rtile * RTILE;
    const float* Xb = X + (size_t)b * CDIM * NPTS;

    float acc[RTILE][4];
    float sqv[4];
#pragma unroll
    for (int r = 0; r < RTILE; r++)
#pragma unroll
        for (int u = 0; u < 4; u++) acc[r][u] = 0.f;
#pragma unroll
    for (int u = 0; u < 4; u++) sqv[u] = 0.f;

    for (int ch = 0; ch < 16; ch++) {
        const int c0 = ch * 4;
#pragma unroll
        for (int cc = 0; cc < 4; cc++) {
            float4 v = *(const float4*)(Xb + (size_t)(c0 + cc) * NPTS + 4 * t);
            *(float4*)&s_fstage[cc][4 * t] = v;
        }
        __syncthreads();
#pragma unroll
        for (int cc = 0; cc < 4; cc++) {
            float4 bv4 = *(const float4*)&s_fstage[cc][4 * t];
            float bv[4] = {bv4.x, bv4.y, bv4.z, bv4.w};
#pragma unroll
            for (int u = 0; u < 4; u++) sqv[u] += bv[u] * bv[u];
            const float* arow = Xb + (size_t)(c0 + cc) * NPTS + r0;
            float4 a0 = *(const float4*)(arow);
            float4 a1 = *(const float4*)(arow + 4);
            float av[8] = {a0.x, a0.y, a0.z, a0.w, a1.x, a1.y, a1.z, a1.w};
#pragma unroll
            for (int r = 0; r < RTILE; r++)
#pragma unroll
                for (int u = 0; u < 4; u++) acc[r][u] += av[r] * bv[u];
        }
        __syncthreads();
    }

    float* s_dist = s_pool;
#pragma unroll
    for (int r = 0; r < RTILE; r++) {
        const int rG = r0 + r;
        float d[4];
#pragma unroll
        for (int u = 0; u < 4; u++) {
            float dd = sqv[u] - 2.f * acc[r][u];
            d[u] = (4 * t + u == rG) ? __uint_as_float(0x7F800000u) : dd;
        }
        *(float4*)&s_dist[r * NPTS + 4 * t] = make_float4(d[0], d[1], d[2], d[3]);
    }
    __syncthreads();

    const int wave = t >> 6, lane = t & 63;
    const unsigned long long ltmask = (1ull << lane) - 1ull;
    for (int rr = 0; rr < 2; rr++) {
        const int row = wave * 2 + rr;
        unsigned key[16];
#pragma unroll
        for (int tt = 0; tt < 16; tt++) {
            unsigned u = __float_as_uint(s_dist[row * NPTS + tt * 64 + lane]);
            key[tt] = (u & 0x80000000u) ? ~u : (u | 0x80000000u);
        }
        unsigned lo = 0u, hi = 0xFFFFFFFFu;
        while (lo < hi) {
            unsigned mid = lo + ((hi - lo) >> 1);
            int cnt = 0;
#pragma unroll
            for (int tt = 0; tt < 16; tt++)
                cnt += __popcll(__ballot(key[tt] <= mid));
            if (cnt >= KNN) hi = mid; else lo = mid + 1;
        }
        const unsigned v49 = lo;
        int cntless = 0;
#pragma unroll
        for (int tt = 0; tt < 16; tt++)
            cntless += __popcll(__ballot(key[tt] < v49));
        const int need = KNN - cntless;
        int base = 0, eqtaken = 0;
#pragma unroll
        for (int tt = 0; tt < 16; tt++) {
            bool islt = key[tt] < v49;
            bool iseq = key[tt] == v49;
            unsigned long long meq = __ballot(iseq);
            int eqrank = eqtaken + __popcll(meq & ltmask);
            bool sel = islt || (iseq && (eqrank < need));
            unsigned long long msel = __ballot(sel);
            if (sel) {
                int pos = base + __popcll(msel & ltmask);
                s_knn[row][pos] = tt * 64 + lane;
            }
            base    += __popcll(msel);
            eqtaken += __popcll(meq);
        }
    }
    __syncthreads();

    float* astage = s_pool;
    float* s_redf = (float*)s_fstage;
    const int ar = t >> 5, acc8 = (t & 31) >> 2, ks = t & 3;
    for (int c0 = 0; c0 < CDIM; c0 += 8) {
#pragma unroll
        for (int qq = 0; qq < 8; qq++) {
            int if4 = qq * 256 + t;
            int cc = if4 >> 8, j4 = if4 & 255;
            float4 v = *(const float4*)(Xb + (size_t)(c0 + cc) * NPTS + 4 * j4);
            *(float4*)&astage[cc * APAD + 4 * j4] = v;
        }
        __syncthreads();
        float partial = 0.f;
        for (int k = ks; k < KNN; k += 4)
            partial += astage[acc8 * APAD + s_knn[ar][k]];
        s_redf[t] = partial;
        __syncthreads();
        if (t < 64) {
            int r = t >> 3, cc = t & 7;
            int bi = r * 32 + cc * 4;
            s_z[r][c0 + cc] = s_redf[bi] + s_redf[bi + 1] + s_redf[bi + 2] + s_redf[bi + 3];
        }
        __syncthreads();
    }

    float* wt = s_pool;
#pragma unroll 4
    for (int qq = 0; qq < 32; qq++) {
        int e = qq * 256 + t;
        int o = e >> 6, c = e & 63;
        wt[c * WPAD + o] = W[e];
    }
    __syncthreads();
    const int o = t & 127, rg = t >> 7;
    float facc[4] = {0.f, 0.f, 0.f, 0.f};
    for (int c = 0; c < CDIM; c += 4) {
        float w0 = wt[(c + 0) * WPAD + o], w1 = wt[(c + 1) * WPAD + o];
        float w2 = wt[(c + 2) * WPAD + o], w3 = wt[(c + 3) * WPAD + o];
#pragma unroll
        for (int qq = 0; qq < 4; qq++) {
            float4 zv = *(const float4*)&s_z[rg * 4 + qq][c];
            facc[qq] += w0 * zv.x + w1 * zv.y + w2 * zv.z + w3 * zv.w;
        }
    }
    const float bo = bias[o];
    float rsum = 0.f;
#pragma unroll
    for (int qq = 0; qq < 4; qq++) {
        float f = facc[qq] * (1.f / KNN) + bo;
        rsum += fmaxf(f, 0.f);
    }
    s_redf[t] = rsum;
    __syncthreads();
    if (t < 128) {
        float scale = gamma[t] * rsqrtf(rvar[t] + BNEPS) * (1.f / NPTS);
        atomicAdd(&out[b * ODIM + t], (s_redf[t] + s_redf[t + 128]) * scale);
    }
}

extern "C" void kernel_launch(void* const* d_in, const int* in_sizes, int n_in,
                              void* d_out, int out_size, void* d_ws, size_t ws_size,
                              hipStream_t stream) {
    const float* X     = (const float*)d_in[0];
    const float* W     = (const float*)d_in[1];
    const float* bias  = (const float*)d_in[2];
    const float* gamma = (const float*)d_in[3];
    const float* beta  = (const float*)d_in[4];
    const float* rmean = (const float*)d_in[5];
    const float* rvar  = (const float*)d_in[6];
    float* out = (float*)d_out;

    if (ws_size >= WS_NEED) {
        uint8_t* ws = (uint8_t*)d_ws;
        uint32_t* XF  = (uint32_t*)(ws + O_XF);
        float*    sqw = (float*)(ws + O_SQ);
        uint32_t* WFh = (uint32_t*)(ws + O_WF);
        uint32_t* WFl = WFh + 16 * 64 * 4;
        uint32_t* XFT = (uint32_t*)(ws + O_XFT);
        k0_split<<<BATCH * 16, 256, 0, stream>>>(X, W, XF, sqw, XFT, WFh, WFl,
                                                 gamma, beta, rmean, rvar, out);
        k1_fused<<<BATCH * 64, 512, 0, stream>>>(XF, sqw, XFT, WFh, WFl,
                                                 bias, gamma, rvar, out);
    } else {
        gcn_init<<<(BATCH * ODIM + 255) / 256, 256, 0, stream>>>(gamma, beta, rmean, rvar, out);
        gcn_main<<<BATCH * (NPTS / RTILE), 256, 0, stream>>>(X, W, bias, gamma, rvar, out);
    }
}

// Round 15
// 230.492 us; speedup vs baseline: 1.0641x; 1.0641x over previous
//
#include <hip/hip_runtime.h>
#include <stdint.h>

#define BATCH 64
#define CDIM  64
#define NPTS  1024
#define ODIM  128
#define KNN   49
#define KNNP  52      // fallback-path knn row stride
#define BNEPS 1e-5f
#define ZPAD  72      // ZF row stride in ushorts (144 B: 16B-aligned, 2-way banks)

typedef __attribute__((ext_vector_type(8))) short bf16x8;   // 8 bf16 (4 VGPRs)
typedef __attribute__((ext_vector_type(4))) float f32x4;
typedef union { bf16x8 v; uint32_t d[4]; } bfu;

__device__ __forceinline__ int mbcnt64(unsigned long long m) {
    return __builtin_amdgcn_mbcnt_hi((uint32_t)(m >> 32),
           __builtin_amdgcn_mbcnt_lo((uint32_t)m, 0));
}

__device__ __forceinline__ void bf16_split(float x, uint32_t& h, uint32_t& l) {
    uint32_t u = __float_as_uint(x);
    h = (u + 0x7FFFu + ((u >> 16) & 1u)) >> 16;      // RTNE bf16 high part
    float hf = __uint_as_float(h << 16);
    uint32_t ul = __float_as_uint(x - hf);
    l = (ul + 0x7FFFu + ((ul >> 16) & 1u)) >> 16;    // RTNE bf16 residual
}

// ---- workspace layout (bytes) ----
#define O_XF   0
#define SZ_XF  (BATCH*64*2*64*8*4)        // 16,777,216  X Gram fragments (k1)
#define O_SQ   (O_XF + SZ_XF)
#define SZ_SQ  (BATCH*NPTS*4)             // 262,144    per-col squared norms
#define O_WF   (O_SQ + SZ_SQ)
#define SZ_WF  (2*16*64*16)               // 32,768  W bf16 hi/lo B-fragments
#define O_BM   (O_WF + SZ_WF)
#define SZ_BM  (BATCH*NPTS*32*4)          // 8,388,608  neighbor bitmaps (32 dw/row)
#define O_XFT  (O_BM + SZ_BM)
#define SZ_XFT (BATCH*32*4*64*8*4)        // 16,777,216 X^T agg B-fragments
#define WS_NEED ((size_t)(O_XFT + SZ_XFT))  // 42,237,952 < proven 47,448,064 grant

// out[b*O+o] = beta - gamma*mean*rsqrt(var+eps)   (fallback path init)
__global__ void gcn_init(const float* __restrict__ gamma, const float* __restrict__ beta,
                         const float* __restrict__ rmean, const float* __restrict__ rvar,
                         float* __restrict__ out) {
    int i = blockIdx.x * 256 + threadIdx.x;
    if (i < BATCH * ODIM) {
        int o = i & (ODIM - 1);
        out[i] = beta[o] - gamma[o] * rmean[o] * rsqrtf(rvar[o] + BNEPS);
    }
}

// ======================= K0: Gram frags + agg B-frags (X^T) + W frags + sq ==============
// Blocks 0-31 also init out (BN constant); blocks 32-35 also write the pre-split W
// B-fragments (WFh/WFl). Every block builds 8 XFT fragment tiles.
__global__ __launch_bounds__(256) void k0_split(const float* __restrict__ X,
                                                const float* __restrict__ W,
                                                uint32_t* __restrict__ XF,
                                                float* __restrict__ sq,
                                                uint32_t* __restrict__ XFT,
                                                uint32_t* __restrict__ WFh,
                                                uint32_t* __restrict__ WFl,
                                                const float* __restrict__ gamma,
                                                const float* __restrict__ beta,
                                                const float* __restrict__ rmean,
                                                const float* __restrict__ rvar,
                                                float* __restrict__ out) {
    if (blockIdx.x < 32) {                           // 32*256 = 8192 = BATCH*ODIM
        int i = blockIdx.x * 256 + threadIdx.x;
        int o = i & (ODIM - 1);
        out[i] = beta[o] - gamma[o] * rmean[o] * rsqrtf(rvar[o] + BNEPS);
    } else if (blockIdx.x < 36) {                    // 4*256 = 1024 = 16 entries x 64 lanes
        int item = (blockIdx.x - 32) * 256 + threadIdx.x;
        int e = item >> 6, ln = item & 63;
        int nt = e >> 1, kt = e & 1;
        int o = nt * 16 + (ln & 15);
        int kc = kt * 32 + (ln >> 4) * 8;            // B-frag: k = quad*8 + j
        const float* wp = W + (size_t)o * CDIM + kc;
        uint32_t h[8], l[8];
#pragma unroll
        for (int jj = 0; jj < 8; jj++) bf16_split(wp[jj], h[jj], l[jj]);
        *(uint4*)&WFh[item * 4] = make_uint4(h[0] | (h[1] << 16), h[2] | (h[3] << 16),
                                             h[4] | (h[5] << 16), h[6] | (h[7] << 16));
        *(uint4*)&WFl[item * 4] = make_uint4(l[0] | (l[1] << 16), l[2] | (l[3] << 16),
                                             l[4] | (l[5] << 16), l[6] | (l[7] << 16));
    }
    const int b    = blockIdx.x >> 4;
    const int g    = blockIdx.x & 15;
    const int wv   = threadIdx.x >> 6;
    const int t16  = g * 4 + wv;
    const int lane = threadIdx.x & 63;
    const int n    = t16 * 16 + (lane & 15);
    const int cg   = lane >> 4;
    const float* Xb = X + (size_t)b * CDIM * NPTS;
    float s = 0.f;
    for (int ks = 0; ks < 2; ks++) {                 // ---- Gram fragments (k1) ----
        uint32_t hi[4], lo[4];
#pragma unroll
        for (int dj = 0; dj < 4; dj++) {
            uint32_t hw[2], lw[2];
#pragma unroll
            for (int e = 0; e < 2; e++) {
                int c = ks * 32 + cg * 8 + dj * 2 + e;
                float x = Xb[(size_t)c * NPTS + n];
                s += x * x;
                bf16_split(x, hw[e], lw[e]);
            }
            hi[dj] = hw[0] | (hw[1] << 16);
            lo[dj] = lw[0] | (lw[1] << 16);
        }
        size_t entry = ((size_t)(b * 64 + t16) * 2 + ks) * 64 + lane;
        uint32_t* p = XF + entry * 8;
        *(uint4*)p       = make_uint4(hi[0], hi[1], hi[2], hi[3]);
        *(uint4*)(p + 4) = make_uint4(lo[0], lo[1], lo[2], lo[3]);
    }
    s += __shfl_xor(s, 16, 64);
    s += __shfl_xor(s, 32, 64);
    if (lane < 16) sq[b * NPTS + n] = s;

    // ---- agg B-fragments: B[k=node][n=channel] = X[c][node], hi/lo split ----
#pragma unroll
    for (int sx = 0; sx < 2; sx++) {
        int task = g * 8 + wv * 2 + sx;              // 0..127 = 32 kt x 4 ct
        int kt = task >> 2, ct = task & 3;
        int c  = ct * 16 + (lane & 15);
        int n0 = kt * 32 + (lane >> 4) * 8;
        const float* xp = Xb + (size_t)c * NPTS + n0;
        uint32_t h[8], l[8];
#pragma unroll
        for (int j = 0; j < 8; j++) bf16_split(xp[j], h[j], l[j]);
        uint32_t* pp = XFT + ((((size_t)b * 32 + kt) * 4 + ct) * 64 + lane) * 8;
        *(uint4*)pp       = make_uint4(h[0] | (h[1] << 16), h[2] | (h[3] << 16),
                                       h[4] | (h[5] << 16), h[6] | (h[7] << 16));
        *(uint4*)(pp + 4) = make_uint4(l[0] | (l[1] << 16), l[2] | (l[3] << 16),
                                       l[4] | (l[5] << 16), l[6] | (l[7] << 16));
    }
}

// ======================= K1: MFMA Gram + 16-bit select -> neighbor bitmap ===============
// Round-8 frozen gram+select core. Emit: __ballot(sel) per (row, tt) IS the row's
// 64-column neighbor bitmap -> staged in LDS, written to BM fully coalesced (int4).
// No knn array, no scattered stores, no 4x RMW write amplification.
__global__ __launch_bounds__(512, 6) void k1_gram_select(const uint32_t* __restrict__ XF,
                                                         const float* __restrict__ sq,
                                                         uint32_t* __restrict__ BM) {
    __shared__ uint32_t s_pk[8 * 1024];              // 32 KB packed keys
    __shared__ uint32_t s_bm[16][32];                // 2 KB row bitmaps
    const int b    = blockIdx.x >> 6;
    const int rt   = blockIdx.x & 63;                // 16-row tile
    const int wave = threadIdx.x >> 6, lane = threadIdx.x & 63;
    const int q = lane >> 4, l15 = lane & 15;

    // ---- Gram (frozen) ----
    bf16x8 ahi[2], alo[2];
#pragma unroll
    for (int ks = 0; ks < 2; ks++) {
        const uint32_t* p = XF + (((size_t)(b * 64 + rt) * 2 + ks) * 64 + lane) * 8;
        ahi[ks] = *(const bf16x8*)p;
        alo[ks] = *(const bf16x8*)(p + 4);
    }
    const float* sqb = sq + b * NPTS;

#pragma unroll
    for (int tt = 0; tt < 8; tt++) {                 // wave's 8 col-tiles
        const int t16 = wave * 8 + tt;
        f32x4 acc = {0.f, 0.f, 0.f, 0.f};
#pragma unroll
        for (int ks = 0; ks < 2; ks++) {
            const uint32_t* p = XF + (((size_t)(b * 64 + t16) * 2 + ks) * 64 + lane) * 8;
            bf16x8 bhi = *(const bf16x8*)p;
            bf16x8 blo = *(const bf16x8*)(p + 4);
            acc = __builtin_amdgcn_mfma_f32_16x16x32_bf16(ahi[ks], bhi, acc, 0, 0, 0);
            acc = __builtin_amdgcn_mfma_f32_16x16x32_bf16(alo[ks], bhi, acc, 0, 0, 0);
            acc = __builtin_amdgcn_mfma_f32_16x16x32_bf16(ahi[ks], blo, acc, 0, 0, 0);
        }
        const int col  = t16 * 16 + l15;
        const float sqv = sqb[col];
        uint32_t k16[4];
#pragma unroll
        for (int i = 0; i < 4; i++) {
            int row = q * 4 + i;                     // C layout: row=(lane>>4)*4+reg
            float d = fmaf(-2.f, acc[i], sqv);       // sq_r dropped (row-monotone)
            if (col == rt * 16 + row) d = __uint_as_float(0x7F800000u);  // self
            uint32_t u = __float_as_uint(d);
            uint32_t key = ((int)u < 0) ? ~u : (u | 0x80000000u);
            k16[i] = key >> 16;                      // 16-bit monotone key
        }
        const int p0 = 2 * q, p1 = 2 * q + 1;        // row pairs (2-way wr conflict: free)
        s_pk[p0 * 1024 + (col ^ ((p0 & 3) << 3))] = k16[0] | (k16[1] << 16);
        s_pk[p1 * 1024 + (col ^ ((p1 & 3) << 3))] = k16[2] | (k16[3] << 16);
    }
    __syncthreads();

    // ---- select (frozen): keys -> regs, narrowed 16-bit binary search ----
    uint32_t k0r[16], k1r[16];
    {
        const int sw = (wave & 3) << 3;
#pragma unroll
        for (int tt = 0; tt < 16; tt++) {
            uint32_t pk = s_pk[wave * 1024 + ((tt * 64 + lane) ^ sw)];
            k0r[tt] = pk & 0xFFFFu;
            k1r[tt] = pk >> 16;
        }
    }

    uint32_t lo0, hi0, lo1, hi1;
    {
        uint32_t lm0 = k0r[0], lm1 = k1r[0];
#pragma unroll
        for (int tt = 1; tt < 16; tt++) {
            lm0 = k0r[tt] < lm0 ? k0r[tt] : lm0;
            lm1 = k1r[tt] < lm1 ? k1r[tt] : lm1;
        }
        uint32_t g0 = lm0, m0 = lm0, g1 = lm1, m1 = lm1;
#pragma unroll
        for (int off = 1; off < 64; off <<= 1) {
            uint32_t a0 = (uint32_t)__shfl_xor((int)g0, off, 64);
            uint32_t b0 = (uint32_t)__shfl_xor((int)m0, off, 64);
            uint32_t a1 = (uint32_t)__shfl_xor((int)g1, off, 64);
            uint32_t b1 = (uint32_t)__shfl_xor((int)m1, off, 64);
            g0 = a0 < g0 ? a0 : g0;  m0 = b0 > m0 ? b0 : m0;
            g1 = a1 < g1 ? a1 : g1;  m1 = b1 > m1 ? b1 : m1;
        }
        lo0 = g0; hi0 = m0;                          // cnt(<=m) >= 64 >= KNN
        lo1 = g1; hi1 = m1;
    }

    for (int it = 0; it < 16; it++) {
        bool a0 = lo0 < hi0, a1 = lo1 < hi1;
        if (!a0 && !a1) break;
        uint32_t mid0 = (lo0 + hi0) >> 1;
        uint32_t mid1 = (lo1 + hi1) >> 1;
        int cnt0 = 0, cnt1 = 0;
#pragma unroll
        for (int tt = 0; tt < 16; tt++) {
            cnt0 += __popcll(__ballot(k0r[tt] <= mid0));
            cnt1 += __popcll(__ballot(k1r[tt] <= mid1));
        }
        if (a0) { if (cnt0 >= KNN) hi0 = mid0; else lo0 = mid0 + 1; }
        if (a1) { if (cnt1 >= KNN) hi1 = mid1; else lo1 = mid1 + 1; }
    }

    // ---- emit: selection ballots -> LDS bitmap (same selection set as knn path) ----
#pragma unroll
    for (int r = 0; r < 2; r++) {
        const int row = wave * 2 + r;
        const uint32_t vstar = r ? lo1 : lo0;
        const uint32_t* k = r ? k1r : k0r;
        int total_lt = 0;
#pragma unroll
        for (int tt = 0; tt < 16; tt++)
            total_lt += __popcll(__ballot(k[tt] < vstar));
        int base_eq = total_lt;                      // total_lt <= 48 by minimality
#pragma unroll
        for (int tt = 0; tt < 16; tt++) {
            bool islt = k[tt] < vstar;
            bool iseq = k[tt] == vstar;
            unsigned long long meq = __ballot(iseq);
            int pos = base_eq + mbcnt64(meq);
            bool sel = islt || (iseq && pos < KNN);
            unsigned long long msel = __ballot(sel);
            if (lane < 2)
                s_bm[row][tt * 2 + lane] = lane ? (uint32_t)(msel >> 32) : (uint32_t)msel;
            base_eq += __popcll(meq);
        }
    }
    __syncthreads();
    if (threadIdx.x < 128) {                         // 512 dwords, fully coalesced
        uint32_t* dst = BM + ((size_t)(b * NPTS + rt * 16) * 32);
        *(uint4*)&dst[threadIdx.x * 4] = *(const uint4*)&((const uint32_t*)s_bm)[threadIdx.x * 4];
    }
}

// ======================= K2: bitmap -> agg-MFMA -> W-GEMM -> relu/BN/pool ===============
// 512 blocks = (b, nq of 128 rows), 256 threads (4 waves). Round-13 tail minus the
// knn read + atomicOr build: bitmap rows load coalesced into padded LDS. Agg as MFMA
// (A synthesized from bitmap bytes, B from XFT; wave = ct), ZF bf16 split, W-GEMM
// with pre-split WF fragments (coalesced), fused relu/bias/BN/pool epilogue.
__global__ __launch_bounds__(256) void k2_agg(const uint32_t* __restrict__ XFT,
                                              const uint32_t* __restrict__ BM,
                                              const uint32_t* __restrict__ WFh,
                                              const uint32_t* __restrict__ WFl,
                                              const float* __restrict__ bias,
                                              const float* __restrict__ gamma,
                                              const float* __restrict__ rvar,
                                              float* __restrict__ out) {
    __shared__ uint32_t bmp[128 * 33];               // 16.9 KB bitmap (padded rows)
    __shared__ __align__(16) uint16_t ZFh[128 * ZPAD];  // 18.4 KB z hi
    __shared__ __align__(16) uint16_t ZFl[128 * ZPAD];  // 18.4 KB z lo
    __shared__ float red[512];
    const int b = blockIdx.x >> 3, nq = blockIdx.x & 7;
    const int t = threadIdx.x;
    const int wave = t >> 6, lane = t & 63;
    const int q = lane >> 4, l15 = lane & 15;

    // ---- coalesced bitmap load -> padded LDS ----
    {
        const uint32_t* src = BM + ((size_t)(b * NPTS + nq * 128) * 32);
#pragma unroll
        for (int kk = 0; kk < 16; kk++) {
            int idx = kk * 256 + t;                  // 0..4095
            uint32_t v = src[idx];
            bmp[(idx >> 5) * 33 + (idx & 31)] = v;
        }
    }
    __syncthreads();

    // ---- aggregation MFMA: wave = channel group ct, 8 row tiles ----
    const int ct = wave;
    f32x4 acc[8];
#pragma unroll
    for (int mt = 0; mt < 8; mt++) acc[mt] = (f32x4){0.f, 0.f, 0.f, 0.f};
    for (int kt = 0; kt < 32; kt++) {
        const uint32_t* p = XFT + ((((size_t)b * 32 + kt) * 4 + ct) * 64 + lane) * 8;
        bf16x8 bhi = *(const bf16x8*)p;
        bf16x8 blo = *(const bf16x8*)(p + 4);
#pragma unroll
        for (int mt = 0; mt < 8; mt++) {
            uint32_t byte = (bmp[(mt * 16 + l15) * 33 + kt] >> (q * 8)) & 0xFFu;
            bfu a;                                   // bf16 1.0 = 0x3F80 per set bit
            a.d[0] = ((byte & 1u)  ? 0x3F80u : 0u) | ((byte & 2u)   ? 0x3F800000u : 0u);
            a.d[1] = ((byte & 4u)  ? 0x3F80u : 0u) | ((byte & 8u)   ? 0x3F800000u : 0u);
            a.d[2] = ((byte & 16u) ? 0x3F80u : 0u) | ((byte & 32u)  ? 0x3F800000u : 0u);
            a.d[3] = ((byte & 64u) ? 0x3F80u : 0u) | ((byte & 128u) ? 0x3F800000u : 0u);
            acc[mt] = __builtin_amdgcn_mfma_f32_16x16x32_bf16(a.v, bhi, acc[mt], 0, 0, 0);
            acc[mt] = __builtin_amdgcn_mfma_f32_16x16x32_bf16(a.v, blo, acc[mt], 0, 0, 0);
        }
    }

    // ---- write z (C layout: row=q*4+reg, col=l15) as bf16 hi/lo ----
#pragma unroll
    for (int mt = 0; mt < 8; mt++) {
#pragma unroll
        for (int reg = 0; reg < 4; reg++) {
            int r = mt * 16 + q * 4 + reg;
            int c = ct * 16 + l15;
            uint32_t h, l;
            bf16_split(acc[mt][reg], h, l);
            ZFh[r * ZPAD + c] = (uint16_t)h;
            ZFl[r * ZPAD + c] = (uint16_t)l;
        }
    }
    __syncthreads();

    // ---- W-GEMM: S[row][o] = sum_c z[row][c] * W[o][c] (3-term hi/lo MFMA) ----
    bf16x8 zah[2][2], zal[2][2];                     // [mt-local][kt]
#pragma unroll
    for (int m2 = 0; m2 < 2; m2++) {
        const int m = (wave * 2 + m2) * 16 + l15;    // A: m=lane&15 within tile
#pragma unroll
        for (int kt = 0; kt < 2; kt++) {
            const int kb = kt * 32 + q * 8;          // A: k=quad*8+j
            zah[m2][kt] = *(const bf16x8*)&ZFh[m * ZPAD + kb];
            zal[m2][kt] = *(const bf16x8*)&ZFl[m * ZPAD + kb];
        }
    }
    const float inv49 = 1.f / KNN;
    float p[8];
#pragma unroll
    for (int nt = 0; nt < 8; nt++) {
        const int o = nt * 16 + l15;                 // B: n=lane&15 within tile
        bfu wh[2], wl[2];
#pragma unroll
        for (int kt = 0; kt < 2; kt++) {             // pre-split W fragments (coalesced)
            const int item = (nt * 2 + kt) * 64 + lane;
            *(uint4*)wh[kt].d = *(const uint4*)&WFh[item * 4];
            *(uint4*)wl[kt].d = *(const uint4*)&WFl[item * 4];
        }
        f32x4 acc0 = {0.f, 0.f, 0.f, 0.f};
        f32x4 acc1 = {0.f, 0.f, 0.f, 0.f};
#pragma unroll
        for (int kt = 0; kt < 2; kt++) {
            acc0 = __builtin_amdgcn_mfma_f32_16x16x32_bf16(zah[0][kt], wh[kt].v, acc0, 0, 0, 0);
            acc0 = __builtin_amdgcn_mfma_f32_16x16x32_bf16(zal[0][kt], wh[kt].v, acc0, 0, 0, 0);
            acc0 = __builtin_amdgcn_mfma_f32_16x16x32_bf16(zah[0][kt], wl[kt].v, acc0, 0, 0, 0);
            acc1 = __builtin_amdgcn_mfma_f32_16x16x32_bf16(zah[1][kt], wh[kt].v, acc1, 0, 0, 0);
            acc1 = __builtin_amdgcn_mfma_f32_16x16x32_bf16(zal[1][kt], wh[kt].v, acc1, 0, 0, 0);
            acc1 = __builtin_amdgcn_mfma_f32_16x16x32_bf16(zah[1][kt], wl[kt].v, acc1, 0, 0, 0);
        }
        const float bo = bias[o];
        float s = 0.f;
#pragma unroll
        for (int reg = 0; reg < 4; reg++) {          // C: row=quad*4+reg, col=l15
            s += fmaxf(fmaf(acc0[reg], inv49, bo), 0.f);
            s += fmaxf(fmaf(acc1[reg], inv49, bo), 0.f);
        }
        p[nt] = s;
    }
#pragma unroll
    for (int nt = 0; nt < 8; nt++) {                 // reduce over quads (rows)
        p[nt] += __shfl_xor(p[nt], 16, 64);
        p[nt] += __shfl_xor(p[nt], 32, 64);
    }
    if (lane < 16) {
#pragma unroll
        for (int nt = 0; nt < 8; nt++)
            red[wave * 128 + nt * 16 + l15] = p[nt];
    }
    __syncthreads();
    if (t < 128) {
        float s = red[t] + red[128 + t] + red[256 + t] + red[384 + t];
        float scale = gamma[t] * rsqrtf(rvar[t] + BNEPS) * (1.f / NPTS);
        atomicAdd(&out[b * ODIM + t], s * scale);
    }
}

// ======================= Fallback: round-1 fused kernel (no workspace) ==================
#define RTILE 8
#define APAD  1028
#define WPAD  132
#define POOLF (64 * WPAD)

__global__ __launch_bounds__(256) void gcn_main(
    const float* __restrict__ X, const float* __restrict__ W,
    const float* __restrict__ bias, const float* __restrict__ gamma,
    const float* __restrict__ rvar, float* __restrict__ out)
{
    __shared__ __align__(16) float s_pool[POOLF];
    __shared__ __align__(16) float s_fstage[4][APAD];
    __shared__ int   s_knn[RTILE][KNN];
    __shared__ float s_z[RTILE][CDIM];

    const int t = threadIdx.x;
    const int b = blockIdx.x >> 7;
    const int rtile = blockIdx.x & 127;
    const int r0 = rtile * RTILE;
    const float* Xb = X + (size_t)b * CDIM * NPTS;

    float acc[RTILE][4];
    float sqv[4];
#pragma unroll
    for (int r = 0; r < RTILE; r++)
#pragma unroll
        for (int u = 0; u < 4; u++) acc[r][u] = 0.f;
#pragma unroll
    for (int u = 0; u < 4; u++) sqv[u] = 0.f;

    for (int ch = 0; ch < 16; ch++) {
        const int c0 = ch * 4;
#pragma unroll
        for (int cc = 0; cc < 4; cc++) {
            float4 v = *(const float4*)(Xb + (size_t)(c0 + cc) * NPTS + 4 * t);
            *(float4*)&s_fstage[cc][4 * t] = v;
        }
        __syncthreads();
#pragma unroll
        for (int cc = 0; cc < 4; cc++) {
            float4 bv4 = *(const float4*)&s_fstage[cc][4 * t];
            float bv[4] = {bv4.x, bv4.y, bv4.z, bv4.w};
#pragma unroll
            for (int u = 0; u < 4; u++) sqv[u] += bv[u] * bv[u];
            const float* arow = Xb + (size_t)(c0 + cc) * NPTS + r0;
            float4 a0 = *(const float4*)(arow);
            float4 a1 = *(const float4*)(arow + 4);
            float av[8] = {a0.x, a0.y, a0.z, a0.w, a1.x, a1.y, a1.z, a1.w};
#pragma unroll
            for (int r = 0; r < RTILE; r++)
#pragma unroll
                for (int u = 0; u < 4; u++) acc[r][u] += av[r] * bv[u];
        }
        __syncthreads();
    }

    float* s_dist = s_pool;
#pragma unroll
    for (int r = 0; r < RTILE; r++) {
        const int rG = r0 + r;
        float d[4];
#pragma unroll
        for (int u = 0; u < 4; u++) {
            float dd = sqv[u] - 2.f * acc[r][u];
            d[u] = (4 * t + u == rG) ? __uint_as_float(0x7F800000u) : dd;
        }
        *(float4*)&s_dist[r * NPTS + 4 * t] = make_float4(d[0], d[1], d[2], d[3]);
    }
    __syncthreads();

    const int wave = t >> 6, lane = t & 63;
    const unsigned long long ltmask = (1ull << lane) - 1ull;
    for (int rr = 0; rr < 2; rr++) {
        const int row = wave * 2 + rr;
        unsigned key[16];
#pragma unroll
        for (int tt = 0; tt < 16; tt++) {
            unsigned u = __float_as_uint(s_dist[row * NPTS + tt * 64 + lane]);
            key[tt] = (u & 0x80000000u) ? ~u : (u | 0x80000000u);
        }
        unsigned lo = 0u, hi = 0xFFFFFFFFu;
        while (lo < hi) {
            unsigned mid = lo + ((hi - lo) >> 1);
            int cnt = 0;
#pragma unroll
            for (int tt = 0; tt < 16; tt++)
                cnt += __popcll(__ballot(key[tt] <= mid));
            if (cnt >= KNN) hi = mid; else lo = mid + 1;
        }
        const unsigned v49 = lo;
        int cntless = 0;
#pragma unroll
        for (int tt = 0; tt < 16; tt++)
            cntless += __popcll(__ballot(key[tt] < v49));
        const int need = KNN - cntless;
        int base = 0, eqtaken = 0;
#pragma unroll
        for (int tt = 0; tt < 16; tt++) {
            bool islt = key[tt] < v49;
            bool iseq = key[tt] == v49;
            unsigned long long meq = __ballot(iseq);
            int eqrank = eqtaken + __popcll(meq & ltmask);
            bool sel = islt || (iseq && (eqrank < need));
            unsigned long long msel = __ballot(sel);
            if (sel) {
                int pos = base + __popcll(msel & ltmask);
                s_knn[row][pos] = tt * 64 + lane;
            }
            base    += __popcll(msel);
            eqtaken += __popcll(meq);
        }
    }
    __syncthreads();

    float* astage = s_pool;
    float* s_redf = (float*)s_fstage;
    const int ar = t >> 5, acc8 = (t & 31) >> 2, ks = t & 3;
    for (int c0 = 0; c0 < CDIM; c0 += 8) {
#pragma unroll
        for (int qq = 0; qq < 8; qq++) {
            int if4 = qq * 256 + t;
            int cc = if4 >> 8, j4 = if4 & 255;
            float4 v = *(const float4*)(Xb + (size_t)(c0 + cc) * NPTS + 4 * j4);
            *(float4*)&astage[cc * APAD + 4 * j4] = v;
        }
        __syncthreads();
        float partial = 0.f;
        for (int k = ks; k < KNN; k += 4)
            partial += astage[acc8 * APAD + s_knn[ar][k]];
        s_redf[t] = partial;
        __syncthreads();
        if (t < 64) {
            int r = t >> 3, cc = t & 7;
            int bi = r * 32 + cc * 4;
            s_z[r][c0 + cc] = s_redf[bi] + s_redf[bi + 1] + s_redf[bi + 2] + s_redf[bi + 3];
        }
        __syncthreads();
    }

    float* wt = s_pool;
#pragma unroll 4
    for (int qq = 0; qq < 32; qq++) {
        int e = qq * 256 + t;
        int o = e >> 6, c = e & 63;
        wt[c * WPAD + o] = W[e];
    }
    __syncthreads();
    const int o = t & 127, rg = t >> 7;
    float facc[4] = {0.f, 0.f, 0.f, 0.f};
    for (int c = 0; c < CDIM; c += 4) {
        float w0 = wt[(c + 0) * WPAD + o], w1 = wt[(c + 1) * WPAD + o];
        float w2 = wt[(c + 2) * WPAD + o], w3 = wt[(c + 3) * WPAD + o];
#pragma unroll
        for (int qq = 0; qq < 4; qq++) {
            float4 zv = *(const float4*)&s_z[rg * 4 + qq][c];
            facc[qq] += w0 * zv.x + w1 * zv.y + w2 * zv.z + w3 * zv.w;
        }
    }
    const float bo = bias[o];
    float rsum = 0.f;
#pragma unroll
    for (int qq = 0; qq < 4; qq++) {
        float f = facc[qq] * (1.f / KNN) + bo;
        rsum += fmaxf(f, 0.f);
    }
    s_redf[t] = rsum;
    __syncthreads();
    if (t < 128) {
        float scale = gamma[t] * rsqrtf(rvar[t] + BNEPS) * (1.f / NPTS);
        atomicAdd(&out[b * ODIM + t], (s_redf[t] + s_redf[t + 128]) * scale);
    }
}

extern "C" void kernel_launch(void* const* d_in, const int* in_sizes, int n_in,
                              void* d_out, int out_size, void* d_ws, size_t ws_size,
                              hipStream_t stream) {
    const float* X     = (const float*)d_in[0];
    const float* W     = (const float*)d_in[1];
    const float* bias  = (const float*)d_in[2];
    const float* gamma = (const float*)d_in[3];
    const float* beta  = (const float*)d_in[4];
    const float* rmean = (const float*)d_in[5];
    const float* rvar  = (const float*)d_in[6];
    float* out = (float*)d_out;

    if (ws_size >= WS_NEED) {
        uint8_t* ws = (uint8_t*)d_ws;
        uint32_t* XF  = (uint32_t*)(ws + O_XF);
        float*    sqw = (float*)(ws + O_SQ);
        uint32_t* WFh = (uint32_t*)(ws + O_WF);
        uint32_t* WFl = WFh + 16 * 64 * 4;
        uint32_t* BM  = (uint32_t*)(ws + O_BM);
        uint32_t* XFT = (uint32_t*)(ws + O_XFT);
        k0_split<<<BATCH * 16, 256, 0, stream>>>(X, W, XF, sqw, XFT, WFh, WFl,
                                                 gamma, beta, rmean, rvar, out);
        k1_gram_select<<<BATCH * 64, 512, 0, stream>>>(XF, sqw, BM);
        k2_agg<<<BATCH * 8, 256, 0, stream>>>(XFT, BM, WFh, WFl, bias, gamma, rvar, out);
    } else {
        gcn_init<<<(BATCH * ODIM + 255) / 256, 256, 0, stream>>>(gamma, beta, rmean, rvar, out);
        gcn_main<<<BATCH * (NPTS / RTILE), 256, 0, stream>>>(X, W, bias, gamma, rvar, out);
    }
}